// Round 7
// baseline (417.490 us; speedup 1.0000x reference)
//
#include <hip/hip_runtime.h>
#include <hip/hip_bf16.h>
#include <stdint.h>

// DynamicSparseAttention MI355X r7 — fp32 I/O.
// r6 failed (absmax 7.7e-3): merged GEMM accumulator multiplied accumulate-
// rounding noise ~4x -> top-64 flips. r7 restores r5's accumulator discipline
// (hh split into two k-range accumulators + separate correction accumulator)
// inside the r6 128x64 global_load_lds GEMM. Attn (bucket select) kept from r6.

typedef __bf16 bf16_t;
typedef bf16_t bf16x8 __attribute__((ext_vector_type(8)));
typedef bf16_t bf16x4 __attribute__((ext_vector_type(4)));
typedef float  f32x4  __attribute__((ext_vector_type(4)));

#define NB 2
#define SS 1024
#define EE 1024
#define NH 16
#define HD 64
#define NBH (NB*NH)
#define NX_ ((size_t)NB*SS*EE)   // 2,097,152
#define NW_ ((size_t)EE*EE)      // 1,048,576

__device__ __forceinline__ f32x4 mfma16(bf16x8 a, bf16x8 b, f32x4 c) {
  return __builtin_amdgcn_mfma_f32_16x16x32_bf16(a, b, c, 0, 0, 0);
}

__device__ __forceinline__ void split3(float x, bf16_t& h, bf16_t& m, bf16_t& l) {
  h = (bf16_t)x;
  float r = x - (float)h;     // exact
  m = (bf16_t)r;
  float r2 = r - (float)m;    // exact
  l = (bf16_t)r2;             // residual <= 2^-27 |x|
}

// wave-local LDS ordering fence (per-wave scratch; no cross-wave deps)
__device__ __forceinline__ void wave_fence() {
  __builtin_amdgcn_wave_barrier();
  __builtin_amdgcn_s_waitcnt(0);
  __builtin_amdgcn_wave_barrier();
}

// async global->LDS, 16B per lane; LDS dest = wave-uniform base + lane*16
__device__ __forceinline__ void gld16(const bf16_t* g, bf16_t* l) {
  __builtin_amdgcn_global_load_lds(
      (const __attribute__((address_space(1))) void*)g,
      (__attribute__((address_space(3))) void*)l, 16, 0, 0);
}

// ---------------------------------------------------------------------------
// fused presplit of x, Wq, Wk, Wv, Wo into h/m/l limb arrays (unchanged)
// ---------------------------------------------------------------------------
__global__ __launch_bounds__(256) void presplit_all(
    const float* __restrict__ x,  const float* __restrict__ wq,
    const float* __restrict__ wk, const float* __restrict__ wv,
    const float* __restrict__ wo, bf16_t* __restrict__ base)
{
  const int blk = blockIdx.x;
  const float* src; bf16_t* h; size_t n; int i;
  if (blk < 2048)      { src = x;  h = base;                   n = NX_; i = blk;        }
  else if (blk < 3072) { src = wq; h = base + 3*NX_;           n = NW_; i = blk - 2048; }
  else if (blk < 4096) { src = wk; h = base + 3*NX_ + 3*NW_;   n = NW_; i = blk - 3072; }
  else if (blk < 5120) { src = wv; h = base + 3*NX_ + 6*NW_;   n = NW_; i = blk - 4096; }
  else                 { src = wo; h = base + 3*NX_ + 9*NW_;   n = NW_; i = blk - 5120; }
  bf16_t* m = h + n;
  bf16_t* l = m + n;
  int idx = i * 256 + threadIdx.x;            // float4 index
  float4 v = ((const float4*)src)[idx];
  float t[4] = { v.x, v.y, v.z, v.w };
  bf16x4 hv, mv, lv;
#pragma unroll
  for (int j = 0; j < 4; j++) {
    bf16_t a, b, c;
    split3(t[j], a, b, c);
    hv[j] = a; mv[j] = b; lv[j] = c;
  }
  ((bf16x4*)h)[idx] = hv;
  ((bf16x4*)m)[idx] = mv;
  ((bf16x4*)l)[idx] = lv;
}

// ---------------------------------------------------------------------------
// NT GEMM, 128x64 tile, global_load_lds staging, r5-grade accumulators:
//   accH0/accH1 = hh products (k<512 / k>=512), accC = corrections.
// C[m,n] = sum_k A[m,k]*W[n,k] + bias[n].  M=2048, N=1024, K=1024.
// NL=3: products hh,hm,mh,hl,lh,mm (q/k path).  NL=2: hh,hm,mh (v/o path).
// 4 waves: wave wv -> M-half (wv&1)*64, N-half (wv>>1)*32; 4x2 16x16 tiles.
// MODE 0: write 3-way-split limbs [B,H,S,HD]; 1: fp32 [B,H,S,HD]; 2: fp32 [M,N]
// ---------------------------------------------------------------------------
template<int MODE, int NL>
__global__ __launch_bounds__(256) void gemm_ldg(
    const bf16_t* __restrict__ Ah, const bf16_t* __restrict__ Am,
    const bf16_t* __restrict__ Al,
    const bf16_t* __restrict__ Bh, const bf16_t* __restrict__ Bm,
    const bf16_t* __restrict__ Bl,
    const float* __restrict__ bias,
    bf16_t* __restrict__ dH, bf16_t* __restrict__ dM, bf16_t* __restrict__ dL,
    float* __restrict__ dF)
{
  __shared__ bf16_t As[NL][128 * 32];   // row-major, unpadded (load-order)
  __shared__ bf16_t Bs[NL][64 * 32];

  const int tid  = threadIdx.x;
  const int wv   = tid >> 6, lane = tid & 63;
  const int quad = lane >> 4, l16 = lane & 15;
  const int m0 = blockIdx.y * 128, n0 = blockIdx.x * 64;
  const int wm = (wv & 1) * 64, wn = (wv >> 1) * 32;

  const bf16_t* AP[3] = { Ah, Am, Al };
  const bf16_t* BP[3] = { Bh, Bm, Bl };

  // staging geometry: lane covers (row = base + lane/4, 16B quarter = lane%4)
  const int arow = wv * 32 + (lane >> 2);
  const int brow = wv * 16 + (lane >> 2);
  const int q8   = (lane & 3) * 8;
  size_t aoff0 = (size_t)(m0 + arow) * 1024 + q8;
  size_t boff  = (size_t)(n0 + brow) * 1024 + q8;

  f32x4 accH0[4][2] = {};   // hh, k < 512
  f32x4 accH1[4][2] = {};   // hh, k >= 512
  f32x4 accC [4][2] = {};   // correction terms (small magnitude)

  for (int k0 = 0; k0 < 1024; k0 += 32) {
    __syncthreads();                     // previous iter's frags consumed
#pragma unroll
    for (int L = 0; L < NL; L++) {
      gld16(AP[L] + aoff0 + k0,              &As[L][(wv * 32) * 32]);
      gld16(AP[L] + aoff0 + 16 * 1024 + k0,  &As[L][(wv * 32 + 16) * 32]);
      gld16(BP[L] + boff + k0,               &Bs[L][(wv * 16) * 32]);
    }
    __syncthreads();                     // staging visible (vmcnt drained)

    bf16x8 bfr[2][3];
#pragma unroll
    for (int nt = 0; nt < 2; nt++)
#pragma unroll
      for (int L = 0; L < NL; L++)
        bfr[nt][L] = *(const bf16x8*)&Bs[L][(wn + nt * 16 + l16) * 32 + quad * 8];

    const bool hi = (k0 >= 512);
#pragma unroll
    for (int mt = 0; mt < 4; mt++) {
      bf16x8 af[3];
#pragma unroll
      for (int L = 0; L < NL; L++)
        af[L] = *(const bf16x8*)&As[L][(wm + mt * 16 + l16) * 32 + quad * 8];
#pragma unroll
      for (int nt = 0; nt < 2; nt++) {
        f32x4& H = hi ? accH1[mt][nt] : accH0[mt][nt];
        H = mfma16(af[0], bfr[nt][0], H);                      // hh
        f32x4 c = accC[mt][nt];
        c = mfma16(af[0], bfr[nt][1], c);                      // hm
        c = mfma16(af[1], bfr[nt][0], c);                      // mh
        if (NL == 3) {
          c = mfma16(af[0], bfr[nt][2], c);                    // hl
          c = mfma16(af[2], bfr[nt][0], c);                    // lh
          c = mfma16(af[1], bfr[nt][1], c);                    // mm
        }
        accC[mt][nt] = c;
      }
    }
  }

  // epilogue: D[row=quad*4+r][col=l16]
#pragma unroll
  for (int mt = 0; mt < 4; mt++)
#pragma unroll
  for (int nt = 0; nt < 2; nt++)
#pragma unroll
  for (int r  = 0; r  < 4;  r++) {
    int gm = m0 + wm + mt * 16 + quad * 4 + r;
    int gn = n0 + wn + nt * 16 + l16;
    float v = (accH0[mt][nt][r] + accH1[mt][nt][r]) + accC[mt][nt][r] + bias[gn];
    if (MODE == 2) {
      dF[(size_t)gm * 1024 + gn] = v;
    } else {
      int b_ = gm >> 10, s_ = gm & 1023, h_ = gn >> 6, d_ = gn & 63;
      size_t di = (((size_t)b_ * NH + h_) * SS + s_) * HD + d_;
      if (MODE == 1) {
        dF[di] = v;
      } else {
        bf16_t hh, mm, ll;
        split3(v, hh, mm, ll);
        dH[di] = hh; dM[di] = mm; dL[di] = ll;
      }
    }
  }
}

// ---------------------------------------------------------------------------
// Fused attention r7 (= r6): per WG = one (b,h) x 16 queries, 512 thr / 8 waves.
// XCD-swizzled. One-shot 512-bin bucket select + exact boundary-bin ranking,
// scratch overlaid on score LDS. LDS = 65792 B -> 2 WG/CU.
// ---------------------------------------------------------------------------
__global__ __launch_bounds__(512, 4) void attn_topk(
    const bf16_t* __restrict__ qhg, const bf16_t* __restrict__ qmg,
    const bf16_t* __restrict__ qlg,
    const bf16_t* __restrict__ khg, const bf16_t* __restrict__ kmg,
    const bf16_t* __restrict__ klg,
    const float*  __restrict__ vg,
    bf16_t* __restrict__ attnH, bf16_t* __restrict__ attnM)
{
  __shared__ float sc[16 * 1028];       // scores; later overlaid as scratch

  const int tid  = threadIdx.x;
  const int wv   = tid >> 6, lane = tid & 63;
  const int quad = lane >> 4, l16 = lane & 15;
  const int xcd = blockIdx.x & 7;
  const int g   = blockIdx.x >> 3;        // 0..255
  const int bh  = xcd + 8 * (g >> 6);     // 0..31 (bh pinned to XCD)
  const int qt  = g & 63;
  const int b_ = bh >> 4, h_ = bh & 15;
  const int q0 = qt * 16;

  // A-frags direct from global: lane holds q[m=l16][k=quad*8+j]
  const size_t qbase = ((size_t)bh * SS + q0 + l16) * HD + quad * 8;
  bf16x8 aH[2], aM[2], aL[2];
#pragma unroll
  for (int ks = 0; ks < 2; ks++) {
    aH[ks] = *(const bf16x8*)(qhg + qbase + ks * 32);
    aM[ks] = *(const bf16x8*)(qmg + qbase + ks * 32);
    aL[ks] = *(const bf16x8*)(qlg + qbase + ks * 32);
  }

  // ---- score phase: wave wv covers keys [wv*128, wv*128+128) ----
  const size_t kwb = ((size_t)bh * SS + wv * 128 + l16) * HD + quad * 8;
#pragma unroll 2
  for (int t2 = 0; t2 < 8; t2++) {
    const size_t kb = kwb + (size_t)t2 * 16 * HD;
    bf16x8 bH0 = *(const bf16x8*)(khg + kb);
    bf16x8 bH1 = *(const bf16x8*)(khg + kb + 32);
    bf16x8 bM0 = *(const bf16x8*)(kmg + kb);
    bf16x8 bM1 = *(const bf16x8*)(kmg + kb + 32);
    bf16x8 bL0 = *(const bf16x8*)(klg + kb);
    bf16x8 bL1 = *(const bf16x8*)(klg + kb + 32);
    f32x4 accA = {}, accB = {}, accC = {};
    accA = mfma16(aH[0], bH0, accA);             // hh, k-half 0
    accB = mfma16(aH[1], bH1, accB);             // hh, k-half 1
    accC = mfma16(aH[0], bM0, accC);             // hm
    accC = mfma16(aH[1], bM1, accC);
    accC = mfma16(aM[0], bH0, accC);             // mh
    accC = mfma16(aM[1], bH1, accC);
    accC = mfma16(aH[0], bL0, accC);             // hl
    accC = mfma16(aH[1], bL1, accC);
    accC = mfma16(aL[0], bH0, accC);             // lh
    accC = mfma16(aL[1], bH1, accC);
    accC = mfma16(aM[0], bM0, accC);             // mm
    accC = mfma16(aM[1], bM1, accC);
    int key = wv * 128 + t2 * 16 + l16;
#pragma unroll
    for (int r = 0; r < 4; r++)
      sc[(quad * 4 + r) * 1028 + key] = ((accA[r] + accB[r]) + accC[r]) * 0.125f;
  }
  __syncthreads();                        // all scores visible

  // preload both owned queries into registers, then sc becomes scratch
  float fv[2][16];
#pragma unroll
  for (int i = 0; i < 16; i++) {
    fv[0][i] = sc[wv * 1028 + i * 64 + lane];
    fv[1][i] = sc[(wv + 8) * 1028 + i * 64 + lane];
  }
  __syncthreads();                        // sc region free for scratch

  // scratch overlay on sc (16448 floats):
  uint32_t* bins  = (uint32_t*)sc + wv * 512;     // [0, 4096) floats
  float*    selWp = sc + 4096;                    // 16*64 fp32  [4096,5120)
  ushort*   selIp = (ushort*)(sc + 5120);         // 16*64 u16
  float*    candV = (float*)bins;                 // reuse bins after scan
  ushort*   candI = (ushort*)(bins + 64);

  const uint64_t lt = (1ull << lane) - 1ull;
  for (int qi = 0; qi < 2; qi++) {
    int q = qi * 8 + wv;
    const float* fq = fv[qi];
    // zero bins (512 u32 per wave)
    *(uint4*)(bins + lane * 8)     = uint4{0, 0, 0, 0};
    *(uint4*)(bins + lane * 8 + 4) = uint4{0, 0, 0, 0};
    wave_fence();
    // histogram: bin = clamp((int)(f*32+256), 0, 511) — monotone in f
#pragma unroll
    for (int i = 0; i < 16; i++) {
      int b = (int)fmaxf(0.f, fminf(511.f, fmaf(fq[i], 32.f, 256.f)));
      atomicAdd(bins + b, 1u);
    }
    wave_fence();
    // descending scan: lane covers bins [504-8*lane, 511-8*lane]
    int base = 504 - 8 * lane;
    uint4 h0 = *(const uint4*)(bins + base);
    uint4 h1 = *(const uint4*)(bins + base + 4);
    uint32_t s_l = h0.x + h0.y + h0.z + h0.w + h1.x + h1.y + h1.z + h1.w;
    uint32_t x = s_l;
#pragma unroll
    for (int off = 1; off < 64; off <<= 1) {
      uint32_t y = __shfl_up(x, off);
      if (lane >= off) x += y;
    }
    uint32_t P = x - s_l;               // count in bins strictly above lane's range
    uint32_t harr[8] = { h1.w, h1.z, h1.y, h1.x, h0.w, h0.z, h0.y, h0.x };
    uint32_t cb = P, G = 0;
    int foundc = -1;
#pragma unroll
    for (int c = 0; c < 8; c++) {
      uint32_t hc = harr[c];
      if (foundc < 0 && (int)cb < 64 && (int)(cb + hc) >= 64) { foundc = c; G = cb; }
      cb += hc;
    }
    uint64_t fm = __ballot(foundc >= 0);
    int src   = __ffsll((unsigned long long)fm) - 1;
    int Bstar = __shfl((foundc >= 0) ? (511 - 8 * lane - foundc) : 0, src);
    int Gs    = __shfl((int)G, src);
    int needed = 64 - Gs;
    wave_fence();                        // scan reads done before candV writes

    // pass 1: bin > Bstar -> selected (Gs total), slots [0, Gs)
    int pos = 0, cT = 0;
#pragma unroll
    for (int i = 0; i < 16; i++) {
      int b = (int)fmaxf(0.f, fminf(511.f, fmaf(fq[i], 32.f, 256.f)));
      bool hi = b > Bstar;
      bool cd = (b == Bstar);
      uint64_t hm = __ballot(hi);
      uint64_t em = __ballot(cd);
      int p  = pos + (int)__popcll(hm & lt);
      int cp = cT  + (int)__popcll(em & lt);
      if (hi) { selWp[q * 64 + p] = fq[i]; selIp[q * 64 + p] = (ushort)(i * 64 + lane); }
      if (cd && cp < 64) { candV[cp] = fq[i]; candI[cp] = (ushort)(i * 64 + lane); }
      pos += (int)__popcll(hm);
      cT  += (int)__popcll(em);
    }
    wave_fence();
    // exact ranking inside boundary bin (value desc, index asc)
    int C = cT < 64 ? cT : 64;
    float mv = candV[lane];
    int   mi = candI[lane];
    int rank = 0;
    for (int i = 0; i < C; i++) {        // LDS broadcast reads
      float ov = candV[i]; int oi = candI[i];
      rank += (ov > mv || (ov == mv && oi < mi)) ? 1 : 0;
    }
    bool take = (lane < C) && (rank < needed);
    uint64_t tm = __ballot(take);
    int slot = Gs + (int)__popcll(tm & lt);
    if (take) { selWp[q * 64 + slot] = mv; selIp[q * 64 + slot] = (ushort)mi; }
    wave_fence();
    // softmax over the 64 selected scores
    float sv = selWp[q * 64 + lane];
    float mx = sv;
#pragma unroll
    for (int off = 32; off >= 1; off >>= 1) mx = fmaxf(mx, __shfl_xor(mx, off));
    float e = __expf(sv - mx);
    float sum = e;
#pragma unroll
    for (int off = 32; off >= 1; off >>= 1) sum += __shfl_xor(sum, off);
    selWp[q * 64 + lane] = e / sum;
    wave_fence();
  }
  __syncthreads();   // PV reads other waves' selW/selIdx

  // ---- PV: thread t -> q = t>>5, j-half = (t>>4)&1, d-block = (t&15)*4 ----
  {
    int q = tid >> 5, jh = (tid >> 4) & 1, dblk = (tid & 15) * 4;
    const float* vb = vg + (size_t)bh * SS * HD;
    f32x4 a4 = {};
#pragma unroll 4
    for (int j = 0; j < 32; j++) {
      int jj = jh * 32 + j;
      float w = selWp[q * 64 + jj];
      int  idx = selIp[q * 64 + jj];
      f32x4 v4 = *(const f32x4*)(vb + (size_t)idx * HD + dblk);
      a4 += w * v4;
    }
#pragma unroll
    for (int c = 0; c < 4; c++) a4[c] += __shfl_xor(a4[c], 16);
    if (jh == 0) {
      size_t dofs = ((size_t)b_ * SS + q0 + q) * EE + h_ * HD + dblk;
      bf16x4 oh, om;
#pragma unroll
      for (int j = 0; j < 4; j++) {
        bf16_t hh = (bf16_t)a4[j];
        oh[j] = hh;
        om[j] = (bf16_t)(a4[j] - (float)hh);
      }
      *(bf16x4*)(attnH + dofs) = oh;
      *(bf16x4*)(attnM + dofs) = om;
    }
  }
}

// ---------------------------------------------------------------------------
extern "C" void kernel_launch(void* const* d_in, const int* in_sizes, int n_in,
                              void* d_out, int out_size, void* d_ws, size_t ws_size,
                              hipStream_t stream)
{
  const float* x  = (const float*)d_in[0];
  const float* Wq = (const float*)d_in[1];
  const float* bq = (const float*)d_in[2];
  const float* Wk = (const float*)d_in[3];
  const float* bk = (const float*)d_in[4];
  const float* Wv = (const float*)d_in[5];
  const float* bv = (const float*)d_in[6];
  const float* Wo = (const float*)d_in[7];
  const float* bo = (const float*)d_in[8];

  bf16_t* base = (bf16_t*)d_ws;
  bf16_t *xh = base,            *xm = xh + NX_,  *xl = xm + NX_;
  bf16_t *wqh = base + 3*NX_,           *wqm = wqh + NW_, *wql = wqm + NW_;
  bf16_t *wkh = base + 3*NX_ + 3*NW_,   *wkm = wkh + NW_, *wkl = wkm + NW_;
  bf16_t *wvh = base + 3*NX_ + 6*NW_,   *wvm = wvh + NW_;
  bf16_t *woh = base + 3*NX_ + 9*NW_,   *wom = woh + NW_;
  bf16_t *p2 = base + 3*NX_ + 12*NW_;
  bf16_t *qh = p2,          *qm = qh + NX_, *ql = qm + NX_;
  bf16_t *kh = ql + NX_,    *km = kh + NX_, *kl = km + NX_;
  float  *vws = (float*)(kl + NX_);
  bf16_t *ath = (bf16_t*)(vws + NX_), *atm = ath + NX_;

  dim3 blk(256);
  presplit_all<<<dim3(6144), blk, 0, stream>>>(x, Wq, Wk, Wv, Wo, base);

  dim3 gg(EE / 64, (NB * SS) / 128);                // 16 x 16 = 256 WGs
  gemm_ldg<0, 3><<<gg, blk, 0, stream>>>(xh, xm, xl, wqh, wqm, wql, bq,
                                         qh, qm, ql, nullptr);
  gemm_ldg<0, 3><<<gg, blk, 0, stream>>>(xh, xm, xl, wkh, wkm, wkl, bk,
                                         kh, km, kl, nullptr);
  gemm_ldg<1, 2><<<gg, blk, 0, stream>>>(xh, xm, nullptr, wvh, wvm, nullptr, bv,
                                         nullptr, nullptr, nullptr, vws);

  attn_topk<<<dim3(NBH * (SS / 16)), dim3(512), 0, stream>>>(
      qh, qm, ql, kh, km, kl, vws, ath, atm);

  gemm_ldg<2, 2><<<gg, blk, 0, stream>>>(ath, atm, nullptr, woh, wom, nullptr, bo,
                                         nullptr, nullptr, nullptr, (float*)d_out);
}

// Round 8
// 325.253 us; speedup vs baseline: 1.2836x; 1.2836x over previous
//
#include <hip/hip_runtime.h>
#include <hip/hip_bf16.h>
#include <stdint.h>

// DynamicSparseAttention MI355X r8 — fp32 I/O.
// r7 @417us: 128x64 gemm_ldg at grid=256 (1 block/CU) exposed the full
// barrier/staging drain every K-step. r8: 64x64 tiles (512 blocks = 2/CU),
// Q+K fused in one launch via blockIdx.z (1024 blocks = 4/CU, shared A in L2),
// global_load_lds staging kept, r7 accumulator discipline kept bit-identical.
// Attn kernel unchanged from r7 (140us, passing).

typedef __bf16 bf16_t;
typedef bf16_t bf16x8 __attribute__((ext_vector_type(8)));
typedef bf16_t bf16x4 __attribute__((ext_vector_type(4)));
typedef float  f32x4  __attribute__((ext_vector_type(4)));

#define NB 2
#define SS 1024
#define EE 1024
#define NH 16
#define HD 64
#define NBH (NB*NH)
#define NX_ ((size_t)NB*SS*EE)   // 2,097,152
#define NW_ ((size_t)EE*EE)      // 1,048,576

__device__ __forceinline__ f32x4 mfma16(bf16x8 a, bf16x8 b, f32x4 c) {
  return __builtin_amdgcn_mfma_f32_16x16x32_bf16(a, b, c, 0, 0, 0);
}

__device__ __forceinline__ void split3(float x, bf16_t& h, bf16_t& m, bf16_t& l) {
  h = (bf16_t)x;
  float r = x - (float)h;     // exact
  m = (bf16_t)r;
  float r2 = r - (float)m;    // exact
  l = (bf16_t)r2;             // residual <= 2^-27 |x|
}

// wave-local LDS ordering fence (per-wave scratch; no cross-wave deps)
__device__ __forceinline__ void wave_fence() {
  __builtin_amdgcn_wave_barrier();
  __builtin_amdgcn_s_waitcnt(0);
  __builtin_amdgcn_wave_barrier();
}

// async global->LDS, 16B per lane; LDS dest = wave-uniform base + lane*16
__device__ __forceinline__ void gld16(const bf16_t* g, bf16_t* l) {
  __builtin_amdgcn_global_load_lds(
      (const __attribute__((address_space(1))) void*)g,
      (__attribute__((address_space(3))) void*)l, 16, 0, 0);
}

// ---------------------------------------------------------------------------
// fused presplit of x, Wq, Wk, Wv, Wo into h/m/l limb arrays (unchanged)
// ---------------------------------------------------------------------------
__global__ __launch_bounds__(256) void presplit_all(
    const float* __restrict__ x,  const float* __restrict__ wq,
    const float* __restrict__ wk, const float* __restrict__ wv,
    const float* __restrict__ wo, bf16_t* __restrict__ base)
{
  const int blk = blockIdx.x;
  const float* src; bf16_t* h; size_t n; int i;
  if (blk < 2048)      { src = x;  h = base;                   n = NX_; i = blk;        }
  else if (blk < 3072) { src = wq; h = base + 3*NX_;           n = NW_; i = blk - 2048; }
  else if (blk < 4096) { src = wk; h = base + 3*NX_ + 3*NW_;   n = NW_; i = blk - 3072; }
  else if (blk < 5120) { src = wv; h = base + 3*NX_ + 6*NW_;   n = NW_; i = blk - 4096; }
  else                 { src = wo; h = base + 3*NX_ + 9*NW_;   n = NW_; i = blk - 5120; }
  bf16_t* m = h + n;
  bf16_t* l = m + n;
  int idx = i * 256 + threadIdx.x;            // float4 index
  float4 v = ((const float4*)src)[idx];
  float t[4] = { v.x, v.y, v.z, v.w };
  bf16x4 hv, mv, lv;
#pragma unroll
  for (int j = 0; j < 4; j++) {
    bf16_t a, b, c;
    split3(t[j], a, b, c);
    hv[j] = a; mv[j] = b; lv[j] = c;
  }
  ((bf16x4*)h)[idx] = hv;
  ((bf16x4*)m)[idx] = mv;
  ((bf16x4*)l)[idx] = lv;
}

// ---------------------------------------------------------------------------
// Fused Q+K projection GEMM. 64x64 tile, grid (16, 32, 2) = 1024 blocks
// (~4/CU). blockIdx.z selects Wq->q or Wk->k. 6 products (hh,hm,mh,hl,lh,mm),
// hh split into k<512 / k>=512 accumulators + correction accumulator (r7
// numerics, bit-identical). global_load_lds(16B) staging, single-buffered.
// 4 waves: wave wv -> (wm,wn) = ((wv&1)*32, (wv>>1)*32), 2x2 16x16 tiles.
// ---------------------------------------------------------------------------
__global__ __launch_bounds__(256, 4) void gemm_qk(
    const bf16_t* __restrict__ Ah, const bf16_t* __restrict__ Am,
    const bf16_t* __restrict__ Al,
    const bf16_t* __restrict__ Bqh, const bf16_t* __restrict__ Bqm,
    const bf16_t* __restrict__ Bql,
    const bf16_t* __restrict__ Bkh, const bf16_t* __restrict__ Bkm,
    const bf16_t* __restrict__ Bkl,
    const float* __restrict__ biasq, const float* __restrict__ biask,
    bf16_t* __restrict__ qH, bf16_t* __restrict__ qM, bf16_t* __restrict__ qL,
    bf16_t* __restrict__ kH, bf16_t* __restrict__ kM, bf16_t* __restrict__ kL)
{
  __shared__ bf16_t As[3][64 * 32];   // row-major, unpadded (gld16 lane order)
  __shared__ bf16_t Bs[3][64 * 32];

  const int z = blockIdx.z;
  const bf16_t* BP[3] = { z ? Bkh : Bqh, z ? Bkm : Bqm, z ? Bkl : Bql };
  const bf16_t* AP[3] = { Ah, Am, Al };
  const float* bias = z ? biask : biasq;
  bf16_t* dH = z ? kH : qH;
  bf16_t* dM = z ? kM : qM;
  bf16_t* dL = z ? kL : qL;

  const int tid  = threadIdx.x;
  const int wv   = tid >> 6, lane = tid & 63;
  const int quad = lane >> 4, l16 = lane & 15;
  const int m0 = blockIdx.y * 64, n0 = blockIdx.x * 64;
  const int wm = (wv & 1) * 32, wn = (wv >> 1) * 32;

  // staging: wave wv covers rows [wv*16, wv*16+16) of each 64x32 array
  const int srow = wv * 16 + (lane >> 2);
  const int q8   = (lane & 3) * 8;
  const size_t aoff = (size_t)(m0 + srow) * 1024 + q8;
  const size_t boff = (size_t)(n0 + srow) * 1024 + q8;

  f32x4 accH0[2][2] = {};   // hh, k < 512
  f32x4 accH1[2][2] = {};   // hh, k >= 512
  f32x4 accC [2][2] = {};   // corrections (small magnitude)

  for (int k0 = 0; k0 < 1024; k0 += 32) {
    __syncthreads();                     // previous iter's frags consumed
#pragma unroll
    for (int L = 0; L < 3; L++) {
      gld16(AP[L] + aoff + k0, &As[L][(wv * 16) * 32]);
      gld16(BP[L] + boff + k0, &Bs[L][(wv * 16) * 32]);
    }
    __syncthreads();                     // staging visible

    bf16x8 bfr[2][3];
#pragma unroll
    for (int nt = 0; nt < 2; nt++)
#pragma unroll
      for (int L = 0; L < 3; L++)
        bfr[nt][L] = *(const bf16x8*)&Bs[L][(wn + nt * 16 + l16) * 32 + quad * 8];

    const bool hi = (k0 >= 512);
#pragma unroll
    for (int mt = 0; mt < 2; mt++) {
      bf16x8 af[3];
#pragma unroll
      for (int L = 0; L < 3; L++)
        af[L] = *(const bf16x8*)&As[L][(wm + mt * 16 + l16) * 32 + quad * 8];
#pragma unroll
      for (int nt = 0; nt < 2; nt++) {
        f32x4& H = hi ? accH1[mt][nt] : accH0[mt][nt];
        H = mfma16(af[0], bfr[nt][0], H);                      // hh
        f32x4 c = accC[mt][nt];
        c = mfma16(af[0], bfr[nt][1], c);                      // hm
        c = mfma16(af[1], bfr[nt][0], c);                      // mh
        c = mfma16(af[0], bfr[nt][2], c);                      // hl
        c = mfma16(af[2], bfr[nt][0], c);                      // lh
        c = mfma16(af[1], bfr[nt][1], c);                      // mm
        accC[mt][nt] = c;
      }
    }
  }

  // epilogue: D[row=quad*4+r][col=l16] -> 3-way split limbs at [B,H,S,HD]
#pragma unroll
  for (int mt = 0; mt < 2; mt++)
#pragma unroll
  for (int nt = 0; nt < 2; nt++)
#pragma unroll
  for (int r  = 0; r  < 4;  r++) {
    int gm = m0 + wm + mt * 16 + quad * 4 + r;
    int gn = n0 + wn + nt * 16 + l16;
    float v = (accH0[mt][nt][r] + accH1[mt][nt][r]) + accC[mt][nt][r] + bias[gn];
    int b_ = gm >> 10, s_ = gm & 1023, h_ = gn >> 6, d_ = gn & 63;
    size_t di = (((size_t)b_ * NH + h_) * SS + s_) * HD + d_;
    bf16_t hh, mm, ll;
    split3(v, hh, mm, ll);
    dH[di] = hh; dM[di] = mm; dL[di] = ll;
  }
}

// ---------------------------------------------------------------------------
// 3-product NT GEMM (hh k-split + hm/mh corrections), 64x64 tile, grid (16,32).
// MODE 1: fp32 [B,H,S,HD] (v-proj).  MODE 2: fp32 row-major [M,N] (o-proj).
// ---------------------------------------------------------------------------
template<int MODE>
__global__ __launch_bounds__(256, 4) void gemm_nl2(
    const bf16_t* __restrict__ Ah, const bf16_t* __restrict__ Am,
    const bf16_t* __restrict__ Bh, const bf16_t* __restrict__ Bm,
    const float* __restrict__ bias, float* __restrict__ dF)
{
  __shared__ bf16_t As[2][64 * 32];
  __shared__ bf16_t Bs[2][64 * 32];

  const bf16_t* AP[2] = { Ah, Am };
  const bf16_t* BP[2] = { Bh, Bm };

  const int tid  = threadIdx.x;
  const int wv   = tid >> 6, lane = tid & 63;
  const int quad = lane >> 4, l16 = lane & 15;
  const int m0 = blockIdx.y * 64, n0 = blockIdx.x * 64;
  const int wm = (wv & 1) * 32, wn = (wv >> 1) * 32;

  const int srow = wv * 16 + (lane >> 2);
  const int q8   = (lane & 3) * 8;
  const size_t aoff = (size_t)(m0 + srow) * 1024 + q8;
  const size_t boff = (size_t)(n0 + srow) * 1024 + q8;

  f32x4 accH0[2][2] = {};
  f32x4 accH1[2][2] = {};
  f32x4 accC [2][2] = {};

  for (int k0 = 0; k0 < 1024; k0 += 32) {
    __syncthreads();
#pragma unroll
    for (int L = 0; L < 2; L++) {
      gld16(AP[L] + aoff + k0, &As[L][(wv * 16) * 32]);
      gld16(BP[L] + boff + k0, &Bs[L][(wv * 16) * 32]);
    }
    __syncthreads();

    bf16x8 bfr[2][2];
#pragma unroll
    for (int nt = 0; nt < 2; nt++)
#pragma unroll
      for (int L = 0; L < 2; L++)
        bfr[nt][L] = *(const bf16x8*)&Bs[L][(wn + nt * 16 + l16) * 32 + quad * 8];

    const bool hi = (k0 >= 512);
#pragma unroll
    for (int mt = 0; mt < 2; mt++) {
      bf16x8 af[2];
#pragma unroll
      for (int L = 0; L < 2; L++)
        af[L] = *(const bf16x8*)&As[L][(wm + mt * 16 + l16) * 32 + quad * 8];
#pragma unroll
      for (int nt = 0; nt < 2; nt++) {
        f32x4& H = hi ? accH1[mt][nt] : accH0[mt][nt];
        H = mfma16(af[0], bfr[nt][0], H);                      // hh
        f32x4 c = accC[mt][nt];
        c = mfma16(af[0], bfr[nt][1], c);                      // hm
        c = mfma16(af[1], bfr[nt][0], c);                      // mh
        accC[mt][nt] = c;
      }
    }
  }

#pragma unroll
  for (int mt = 0; mt < 2; mt++)
#pragma unroll
  for (int nt = 0; nt < 2; nt++)
#pragma unroll
  for (int r  = 0; r  < 4;  r++) {
    int gm = m0 + wm + mt * 16 + quad * 4 + r;
    int gn = n0 + wn + nt * 16 + l16;
    float v = (accH0[mt][nt][r] + accH1[mt][nt][r]) + accC[mt][nt][r] + bias[gn];
    if (MODE == 2) {
      dF[(size_t)gm * 1024 + gn] = v;
    } else {
      int b_ = gm >> 10, s_ = gm & 1023, h_ = gn >> 6, d_ = gn & 63;
      dF[(((size_t)b_ * NH + h_) * SS + s_) * HD + d_] = v;
    }
  }
}

// ---------------------------------------------------------------------------
// Fused attention (r7, unchanged): one (b,h) x 16 queries, 512 thr / 8 waves.
// XCD-swizzled. One-shot 512-bin bucket select + exact boundary-bin ranking,
// scratch overlaid on score LDS. LDS = 65792 B -> 2 WG/CU.
// ---------------------------------------------------------------------------
__global__ __launch_bounds__(512, 4) void attn_topk(
    const bf16_t* __restrict__ qhg, const bf16_t* __restrict__ qmg,
    const bf16_t* __restrict__ qlg,
    const bf16_t* __restrict__ khg, const bf16_t* __restrict__ kmg,
    const bf16_t* __restrict__ klg,
    const float*  __restrict__ vg,
    bf16_t* __restrict__ attnH, bf16_t* __restrict__ attnM)
{
  __shared__ float sc[16 * 1028];       // scores; later overlaid as scratch

  const int tid  = threadIdx.x;
  const int wv   = tid >> 6, lane = tid & 63;
  const int quad = lane >> 4, l16 = lane & 15;
  const int xcd = blockIdx.x & 7;
  const int g   = blockIdx.x >> 3;        // 0..255
  const int bh  = xcd + 8 * (g >> 6);     // 0..31 (bh pinned to XCD)
  const int qt  = g & 63;
  const int b_ = bh >> 4, h_ = bh & 15;
  const int q0 = qt * 16;

  // A-frags direct from global: lane holds q[m=l16][k=quad*8+j]
  const size_t qbase = ((size_t)bh * SS + q0 + l16) * HD + quad * 8;
  bf16x8 aH[2], aM[2], aL[2];
#pragma unroll
  for (int ks = 0; ks < 2; ks++) {
    aH[ks] = *(const bf16x8*)(qhg + qbase + ks * 32);
    aM[ks] = *(const bf16x8*)(qmg + qbase + ks * 32);
    aL[ks] = *(const bf16x8*)(qlg + qbase + ks * 32);
  }

  // ---- score phase: wave wv covers keys [wv*128, wv*128+128) ----
  const size_t kwb = ((size_t)bh * SS + wv * 128 + l16) * HD + quad * 8;
#pragma unroll 2
  for (int t2 = 0; t2 < 8; t2++) {
    const size_t kb = kwb + (size_t)t2 * 16 * HD;
    bf16x8 bH0 = *(const bf16x8*)(khg + kb);
    bf16x8 bH1 = *(const bf16x8*)(khg + kb + 32);
    bf16x8 bM0 = *(const bf16x8*)(kmg + kb);
    bf16x8 bM1 = *(const bf16x8*)(kmg + kb + 32);
    bf16x8 bL0 = *(const bf16x8*)(klg + kb);
    bf16x8 bL1 = *(const bf16x8*)(klg + kb + 32);
    f32x4 accA = {}, accB = {}, accC = {};
    accA = mfma16(aH[0], bH0, accA);             // hh, k-half 0
    accB = mfma16(aH[1], bH1, accB);             // hh, k-half 1
    accC = mfma16(aH[0], bM0, accC);             // hm
    accC = mfma16(aH[1], bM1, accC);
    accC = mfma16(aM[0], bH0, accC);             // mh
    accC = mfma16(aM[1], bH1, accC);
    accC = mfma16(aH[0], bL0, accC);             // hl
    accC = mfma16(aH[1], bL1, accC);
    accC = mfma16(aL[0], bH0, accC);             // lh
    accC = mfma16(aL[1], bH1, accC);
    accC = mfma16(aM[0], bM0, accC);             // mm
    accC = mfma16(aM[1], bM1, accC);
    int key = wv * 128 + t2 * 16 + l16;
#pragma unroll
    for (int r = 0; r < 4; r++)
      sc[(quad * 4 + r) * 1028 + key] = ((accA[r] + accB[r]) + accC[r]) * 0.125f;
  }
  __syncthreads();                        // all scores visible

  // preload both owned queries into registers, then sc becomes scratch
  float fv[2][16];
#pragma unroll
  for (int i = 0; i < 16; i++) {
    fv[0][i] = sc[wv * 1028 + i * 64 + lane];
    fv[1][i] = sc[(wv + 8) * 1028 + i * 64 + lane];
  }
  __syncthreads();                        // sc region free for scratch

  // scratch overlay on sc (16448 floats):
  uint32_t* bins  = (uint32_t*)sc + wv * 512;     // [0, 4096) floats
  float*    selWp = sc + 4096;                    // 16*64 fp32  [4096,5120)
  ushort*   selIp = (ushort*)(sc + 5120);         // 16*64 u16
  float*    candV = (float*)bins;                 // reuse bins after scan
  ushort*   candI = (ushort*)(bins + 64);

  const uint64_t lt = (1ull << lane) - 1ull;
  for (int qi = 0; qi < 2; qi++) {
    int q = qi * 8 + wv;
    const float* fq = fv[qi];
    // zero bins (512 u32 per wave)
    *(uint4*)(bins + lane * 8)     = uint4{0, 0, 0, 0};
    *(uint4*)(bins + lane * 8 + 4) = uint4{0, 0, 0, 0};
    wave_fence();
    // histogram: bin = clamp((int)(f*32+256), 0, 511) — monotone in f
#pragma unroll
    for (int i = 0; i < 16; i++) {
      int b = (int)fmaxf(0.f, fminf(511.f, fmaf(fq[i], 32.f, 256.f)));
      atomicAdd(bins + b, 1u);
    }
    wave_fence();
    // descending scan: lane covers bins [504-8*lane, 511-8*lane]
    int base = 504 - 8 * lane;
    uint4 h0 = *(const uint4*)(bins + base);
    uint4 h1 = *(const uint4*)(bins + base + 4);
    uint32_t s_l = h0.x + h0.y + h0.z + h0.w + h1.x + h1.y + h1.z + h1.w;
    uint32_t x = s_l;
#pragma unroll
    for (int off = 1; off < 64; off <<= 1) {
      uint32_t y = __shfl_up(x, off);
      if (lane >= off) x += y;
    }
    uint32_t P = x - s_l;               // count in bins strictly above lane's range
    uint32_t harr[8] = { h1.w, h1.z, h1.y, h1.x, h0.w, h0.z, h0.y, h0.x };
    uint32_t cb = P, G = 0;
    int foundc = -1;
#pragma unroll
    for (int c = 0; c < 8; c++) {
      uint32_t hc = harr[c];
      if (foundc < 0 && (int)cb < 64 && (int)(cb + hc) >= 64) { foundc = c; G = cb; }
      cb += hc;
    }
    uint64_t fm = __ballot(foundc >= 0);
    int src   = __ffsll((unsigned long long)fm) - 1;
    int Bstar = __shfl((foundc >= 0) ? (511 - 8 * lane - foundc) : 0, src);
    int Gs    = __shfl((int)G, src);
    int needed = 64 - Gs;
    wave_fence();                        // scan reads done before candV writes

    // pass 1: bin > Bstar -> selected (Gs total), slots [0, Gs)
    int pos = 0, cT = 0;
#pragma unroll
    for (int i = 0; i < 16; i++) {
      int b = (int)fmaxf(0.f, fminf(511.f, fmaf(fq[i], 32.f, 256.f)));
      bool hi = b > Bstar;
      bool cd = (b == Bstar);
      uint64_t hm = __ballot(hi);
      uint64_t em = __ballot(cd);
      int p  = pos + (int)__popcll(hm & lt);
      int cp = cT  + (int)__popcll(em & lt);
      if (hi) { selWp[q * 64 + p] = fq[i]; selIp[q * 64 + p] = (ushort)(i * 64 + lane); }
      if (cd && cp < 64) { candV[cp] = fq[i]; candI[cp] = (ushort)(i * 64 + lane); }
      pos += (int)__popcll(hm);
      cT  += (int)__popcll(em);
    }
    wave_fence();
    // exact ranking inside boundary bin (value desc, index asc)
    int C = cT < 64 ? cT : 64;
    float mv = candV[lane];
    int   mi = candI[lane];
    int rank = 0;
    for (int i = 0; i < C; i++) {        // LDS broadcast reads
      float ov = candV[i]; int oi = candI[i];
      rank += (ov > mv || (ov == mv && oi < mi)) ? 1 : 0;
    }
    bool take = (lane < C) && (rank < needed);
    uint64_t tm = __ballot(take);
    int slot = Gs + (int)__popcll(tm & lt);
    if (take) { selWp[q * 64 + slot] = mv; selIp[q * 64 + slot] = (ushort)mi; }
    wave_fence();
    // softmax over the 64 selected scores
    float sv = selWp[q * 64 + lane];
    float mx = sv;
#pragma unroll
    for (int off = 32; off >= 1; off >>= 1) mx = fmaxf(mx, __shfl_xor(mx, off));
    float e = __expf(sv - mx);
    float sum = e;
#pragma unroll
    for (int off = 32; off >= 1; off >>= 1) sum += __shfl_xor(sum, off);
    selWp[q * 64 + lane] = e / sum;
    wave_fence();
  }
  __syncthreads();   // PV reads other waves' selW/selIdx

  // ---- PV: thread t -> q = t>>5, j-half = (t>>4)&1, d-block = (t&15)*4 ----
  {
    int q = tid >> 5, jh = (tid >> 4) & 1, dblk = (tid & 15) * 4;
    const float* vb = vg + (size_t)bh * SS * HD;
    f32x4 a4 = {};
#pragma unroll 4
    for (int j = 0; j < 32; j++) {
      int jj = jh * 32 + j;
      float w = selWp[q * 64 + jj];
      int  idx = selIp[q * 64 + jj];
      f32x4 v4 = *(const f32x4*)(vb + (size_t)idx * HD + dblk);
      a4 += w * v4;
    }
#pragma unroll
    for (int c = 0; c < 4; c++) a4[c] += __shfl_xor(a4[c], 16);
    if (jh == 0) {
      size_t dofs = ((size_t)b_ * SS + q0 + q) * EE + h_ * HD + dblk;
      bf16x4 oh, om;
#pragma unroll
      for (int j = 0; j < 4; j++) {
        bf16_t hh = (bf16_t)a4[j];
        oh[j] = hh;
        om[j] = (bf16_t)(a4[j] - (float)hh);
      }
      *(bf16x4*)(attnH + dofs) = oh;
      *(bf16x4*)(attnM + dofs) = om;
    }
  }
}

// ---------------------------------------------------------------------------
extern "C" void kernel_launch(void* const* d_in, const int* in_sizes, int n_in,
                              void* d_out, int out_size, void* d_ws, size_t ws_size,
                              hipStream_t stream)
{
  const float* x  = (const float*)d_in[0];
  const float* Wq = (const float*)d_in[1];
  const float* bq = (const float*)d_in[2];
  const float* Wk = (const float*)d_in[3];
  const float* bk = (const float*)d_in[4];
  const float* Wv = (const float*)d_in[5];
  const float* bv = (const float*)d_in[6];
  const float* Wo = (const float*)d_in[7];
  const float* bo = (const float*)d_in[8];

  bf16_t* base = (bf16_t*)d_ws;
  bf16_t *xh = base,            *xm = xh + NX_,  *xl = xm + NX_;
  bf16_t *wqh = base + 3*NX_,           *wqm = wqh + NW_, *wql = wqm + NW_;
  bf16_t *wkh = base + 3*NX_ + 3*NW_,   *wkm = wkh + NW_, *wkl = wkm + NW_;
  bf16_t *wvh = base + 3*NX_ + 6*NW_,   *wvm = wvh + NW_;
  bf16_t *woh = base + 3*NX_ + 9*NW_,   *wom = woh + NW_;
  bf16_t *p2 = base + 3*NX_ + 12*NW_;
  bf16_t *qh = p2,          *qm = qh + NX_, *ql = qm + NX_;
  bf16_t *kh = ql + NX_,    *km = kh + NX_, *kl = km + NX_;
  float  *vws = (float*)(kl + NX_);
  bf16_t *ath = (bf16_t*)(vws + NX_), *atm = ath + NX_;

  dim3 blk(256);
  presplit_all<<<dim3(6144), blk, 0, stream>>>(x, Wq, Wk, Wv, Wo, base);

  // fused Q+K: grid (16, 32, 2) = 1024 blocks (~4/CU)
  gemm_qk<<<dim3(EE / 64, (NB * SS) / 64, 2), blk, 0, stream>>>(
      xh, xm, xl, wqh, wqm, wql, wkh, wkm, wkl, bq, bk,
      qh, qm, ql, kh, km, kl);

  // V: grid (16, 32) = 512 blocks (2/CU)
  gemm_nl2<1><<<dim3(EE / 64, (NB * SS) / 64), blk, 0, stream>>>(
      xh, xm, wvh, wvm, bv, vws);

  attn_topk<<<dim3(NBH * (SS / 16)), dim3(512), 0, stream>>>(
      qh, qm, ql, kh, km, kl, vws, ath, atm);

  // O: grid (16, 32) = 512 blocks (2/CU)
  gemm_nl2<2><<<dim3(EE / 64, (NB * SS) / 64), blk, 0, stream>>>(
      ath, atm, woh, wom, bo, (float*)d_out);
}

// Round 9
// 322.549 us; speedup vs baseline: 1.2943x; 1.0084x over previous
//
#include <hip/hip_runtime.h>
#include <hip/hip_bf16.h>
#include <stdint.h>

// DynamicSparseAttention MI355X r9 — fp32 I/O.
// r8 @325us. r9: (1) qk-GEMM -> 128x64 tile at 2 blocks/CU (z-fused grid 512;
// r7's 128-tile failed only from 1 block/CU), numerics bit-identical;
// (2) attn PV 16-deep batched gather prefetch; (3) attn score loop unroll 4.
// v/o GEMMs (64^2, 2/CU), presplit, selection: unchanged from r8.

typedef __bf16 bf16_t;
typedef bf16_t bf16x8 __attribute__((ext_vector_type(8)));
typedef bf16_t bf16x4 __attribute__((ext_vector_type(4)));
typedef float  f32x4  __attribute__((ext_vector_type(4)));

#define NB 2
#define SS 1024
#define EE 1024
#define NH 16
#define HD 64
#define NBH (NB*NH)
#define NX_ ((size_t)NB*SS*EE)   // 2,097,152
#define NW_ ((size_t)EE*EE)      // 1,048,576

__device__ __forceinline__ f32x4 mfma16(bf16x8 a, bf16x8 b, f32x4 c) {
  return __builtin_amdgcn_mfma_f32_16x16x32_bf16(a, b, c, 0, 0, 0);
}

__device__ __forceinline__ void split3(float x, bf16_t& h, bf16_t& m, bf16_t& l) {
  h = (bf16_t)x;
  float r = x - (float)h;     // exact
  m = (bf16_t)r;
  float r2 = r - (float)m;    // exact
  l = (bf16_t)r2;             // residual <= 2^-27 |x|
}

// wave-local LDS ordering fence (per-wave scratch; no cross-wave deps)
__device__ __forceinline__ void wave_fence() {
  __builtin_amdgcn_wave_barrier();
  __builtin_amdgcn_s_waitcnt(0);
  __builtin_amdgcn_wave_barrier();
}

// async global->LDS, 16B per lane; LDS dest = wave-uniform base + lane*16
__device__ __forceinline__ void gld16(const bf16_t* g, bf16_t* l) {
  __builtin_amdgcn_global_load_lds(
      (const __attribute__((address_space(1))) void*)g,
      (__attribute__((address_space(3))) void*)l, 16, 0, 0);
}

// ---------------------------------------------------------------------------
// fused presplit of x, Wq, Wk, Wv, Wo into h/m/l limb arrays (unchanged)
// ---------------------------------------------------------------------------
__global__ __launch_bounds__(256) void presplit_all(
    const float* __restrict__ x,  const float* __restrict__ wq,
    const float* __restrict__ wk, const float* __restrict__ wv,
    const float* __restrict__ wo, bf16_t* __restrict__ base)
{
  const int blk = blockIdx.x;
  const float* src; bf16_t* h; size_t n; int i;
  if (blk < 2048)      { src = x;  h = base;                   n = NX_; i = blk;        }
  else if (blk < 3072) { src = wq; h = base + 3*NX_;           n = NW_; i = blk - 2048; }
  else if (blk < 4096) { src = wk; h = base + 3*NX_ + 3*NW_;   n = NW_; i = blk - 3072; }
  else if (blk < 5120) { src = wv; h = base + 3*NX_ + 6*NW_;   n = NW_; i = blk - 4096; }
  else                 { src = wo; h = base + 3*NX_ + 9*NW_;   n = NW_; i = blk - 5120; }
  bf16_t* m = h + n;
  bf16_t* l = m + n;
  int idx = i * 256 + threadIdx.x;            // float4 index
  float4 v = ((const float4*)src)[idx];
  float t[4] = { v.x, v.y, v.z, v.w };
  bf16x4 hv, mv, lv;
#pragma unroll
  for (int j = 0; j < 4; j++) {
    bf16_t a, b, c;
    split3(t[j], a, b, c);
    hv[j] = a; mv[j] = b; lv[j] = c;
  }
  ((bf16x4*)h)[idx] = hv;
  ((bf16x4*)m)[idx] = mv;
  ((bf16x4*)l)[idx] = lv;
}

// ---------------------------------------------------------------------------
// Fused Q+K projection GEMM, 128x64 tile. grid (16, 16, 2) = 512 blocks
// (exactly 2/CU co-resident). blockIdx.z selects Wq->q or Wk->k.
// 6 products (hh,hm,mh,hl,lh,mm); hh split k<512 / k>=512 + correction acc
// (bit-identical to r8). global_load_lds(16B) staging, single-buffered.
// 4 waves: wave wv -> M-half (wv&1)*64 (4 mt tiles), N-half (wv>>1)*32 (2 nt).
// ---------------------------------------------------------------------------
__global__ __launch_bounds__(256, 2) void gemm_qk(
    const bf16_t* __restrict__ Ah, const bf16_t* __restrict__ Am,
    const bf16_t* __restrict__ Al,
    const bf16_t* __restrict__ Bqh, const bf16_t* __restrict__ Bqm,
    const bf16_t* __restrict__ Bql,
    const bf16_t* __restrict__ Bkh, const bf16_t* __restrict__ Bkm,
    const bf16_t* __restrict__ Bkl,
    const float* __restrict__ biasq, const float* __restrict__ biask,
    bf16_t* __restrict__ qH, bf16_t* __restrict__ qM, bf16_t* __restrict__ qL,
    bf16_t* __restrict__ kH, bf16_t* __restrict__ kM, bf16_t* __restrict__ kL)
{
  __shared__ bf16_t As[3][128 * 32];   // row-major, unpadded (gld16 lane order)
  __shared__ bf16_t Bs[3][64 * 32];

  const int z = blockIdx.z;
  const bf16_t* AP[3] = { Ah, Am, Al };
  const bf16_t* BP[3] = { z ? Bkh : Bqh, z ? Bkm : Bqm, z ? Bkl : Bql };
  const float* bias = z ? biask : biasq;
  bf16_t* dH = z ? kH : qH;
  bf16_t* dM = z ? kM : qM;
  bf16_t* dL = z ? kL : qL;

  const int tid  = threadIdx.x;
  const int wv   = tid >> 6, lane = tid & 63;
  const int quad = lane >> 4, l16 = lane & 15;
  const int m0 = blockIdx.y * 128, n0 = blockIdx.x * 64;
  const int wm = (wv & 1) * 64, wn = (wv >> 1) * 32;

  // staging: A rows [wv*32, wv*32+32) via two gld16; B rows [wv*16, wv*16+16)
  const int arow = wv * 32 + (lane >> 2);
  const int brow = wv * 16 + (lane >> 2);
  const int q8   = (lane & 3) * 8;
  const size_t aoff0 = (size_t)(m0 + arow) * 1024 + q8;
  const size_t boff  = (size_t)(n0 + brow) * 1024 + q8;

  f32x4 accH0[4][2] = {};   // hh, k < 512
  f32x4 accH1[4][2] = {};   // hh, k >= 512
  f32x4 accC [4][2] = {};   // corrections (small magnitude)

  for (int k0 = 0; k0 < 1024; k0 += 32) {
    __syncthreads();                     // previous iter's frags consumed
#pragma unroll
    for (int L = 0; L < 3; L++) {
      gld16(AP[L] + aoff0 + k0,              &As[L][(wv * 32) * 32]);
      gld16(AP[L] + aoff0 + 16 * 1024 + k0,  &As[L][(wv * 32 + 16) * 32]);
      gld16(BP[L] + boff + k0,               &Bs[L][(wv * 16) * 32]);
    }
    __syncthreads();                     // staging visible

    bf16x8 bfr[2][3];
#pragma unroll
    for (int nt = 0; nt < 2; nt++)
#pragma unroll
      for (int L = 0; L < 3; L++)
        bfr[nt][L] = *(const bf16x8*)&Bs[L][(wn + nt * 16 + l16) * 32 + quad * 8];

    const bool hi = (k0 >= 512);
#pragma unroll
    for (int mt = 0; mt < 4; mt++) {
      bf16x8 af[3];
#pragma unroll
      for (int L = 0; L < 3; L++)
        af[L] = *(const bf16x8*)&As[L][(wm + mt * 16 + l16) * 32 + quad * 8];
#pragma unroll
      for (int nt = 0; nt < 2; nt++) {
        f32x4& H = hi ? accH1[mt][nt] : accH0[mt][nt];
        H = mfma16(af[0], bfr[nt][0], H);                      // hh
        f32x4 c = accC[mt][nt];
        c = mfma16(af[0], bfr[nt][1], c);                      // hm
        c = mfma16(af[1], bfr[nt][0], c);                      // mh
        c = mfma16(af[0], bfr[nt][2], c);                      // hl
        c = mfma16(af[2], bfr[nt][0], c);                      // lh
        c = mfma16(af[1], bfr[nt][1], c);                      // mm
        accC[mt][nt] = c;
      }
    }
  }

  // epilogue: D[row=quad*4+r][col=l16] -> 3-way split limbs at [B,H,S,HD]
#pragma unroll
  for (int mt = 0; mt < 4; mt++)
#pragma unroll
  for (int nt = 0; nt < 2; nt++)
#pragma unroll
  for (int r  = 0; r  < 4;  r++) {
    int gm = m0 + wm + mt * 16 + quad * 4 + r;
    int gn = n0 + wn + nt * 16 + l16;
    float v = (accH0[mt][nt][r] + accH1[mt][nt][r]) + accC[mt][nt][r] + bias[gn];
    int b_ = gm >> 10, s_ = gm & 1023, h_ = gn >> 6, d_ = gn & 63;
    size_t di = (((size_t)b_ * NH + h_) * SS + s_) * HD + d_;
    bf16_t hh, mm, ll;
    split3(v, hh, mm, ll);
    dH[di] = hh; dM[di] = mm; dL[di] = ll;
  }
}

// ---------------------------------------------------------------------------
// 3-product NT GEMM (hh k-split + hm/mh corrections), 64x64 tile, grid (16,32).
// MODE 1: fp32 [B,H,S,HD] (v-proj).  MODE 2: fp32 row-major [M,N] (o-proj).
// (unchanged from r8)
// ---------------------------------------------------------------------------
template<int MODE>
__global__ __launch_bounds__(256, 4) void gemm_nl2(
    const bf16_t* __restrict__ Ah, const bf16_t* __restrict__ Am,
    const bf16_t* __restrict__ Bh, const bf16_t* __restrict__ Bm,
    const float* __restrict__ bias, float* __restrict__ dF)
{
  __shared__ bf16_t As[2][64 * 32];
  __shared__ bf16_t Bs[2][64 * 32];

  const bf16_t* AP[2] = { Ah, Am };
  const bf16_t* BP[2] = { Bh, Bm };

  const int tid  = threadIdx.x;
  const int wv   = tid >> 6, lane = tid & 63;
  const int quad = lane >> 4, l16 = lane & 15;
  const int m0 = blockIdx.y * 64, n0 = blockIdx.x * 64;
  const int wm = (wv & 1) * 32, wn = (wv >> 1) * 32;

  const int srow = wv * 16 + (lane >> 2);
  const int q8   = (lane & 3) * 8;
  const size_t aoff = (size_t)(m0 + srow) * 1024 + q8;
  const size_t boff = (size_t)(n0 + srow) * 1024 + q8;

  f32x4 accH0[2][2] = {};
  f32x4 accH1[2][2] = {};
  f32x4 accC [2][2] = {};

  for (int k0 = 0; k0 < 1024; k0 += 32) {
    __syncthreads();
#pragma unroll
    for (int L = 0; L < 2; L++) {
      gld16(AP[L] + aoff + k0, &As[L][(wv * 16) * 32]);
      gld16(BP[L] + boff + k0, &Bs[L][(wv * 16) * 32]);
    }
    __syncthreads();

    bf16x8 bfr[2][2];
#pragma unroll
    for (int nt = 0; nt < 2; nt++)
#pragma unroll
      for (int L = 0; L < 2; L++)
        bfr[nt][L] = *(const bf16x8*)&Bs[L][(wn + nt * 16 + l16) * 32 + quad * 8];

    const bool hi = (k0 >= 512);
#pragma unroll
    for (int mt = 0; mt < 2; mt++) {
      bf16x8 af[2];
#pragma unroll
      for (int L = 0; L < 2; L++)
        af[L] = *(const bf16x8*)&As[L][(wm + mt * 16 + l16) * 32 + quad * 8];
#pragma unroll
      for (int nt = 0; nt < 2; nt++) {
        f32x4& H = hi ? accH1[mt][nt] : accH0[mt][nt];
        H = mfma16(af[0], bfr[nt][0], H);                      // hh
        f32x4 c = accC[mt][nt];
        c = mfma16(af[0], bfr[nt][1], c);                      // hm
        c = mfma16(af[1], bfr[nt][0], c);                      // mh
        accC[mt][nt] = c;
      }
    }
  }

#pragma unroll
  for (int mt = 0; mt < 2; mt++)
#pragma unroll
  for (int nt = 0; nt < 2; nt++)
#pragma unroll
  for (int r  = 0; r  < 4;  r++) {
    int gm = m0 + wm + mt * 16 + quad * 4 + r;
    int gn = n0 + wn + nt * 16 + l16;
    float v = (accH0[mt][nt][r] + accH1[mt][nt][r]) + accC[mt][nt][r] + bias[gn];
    if (MODE == 2) {
      dF[(size_t)gm * 1024 + gn] = v;
    } else {
      int b_ = gm >> 10, s_ = gm & 1023, h_ = gn >> 6, d_ = gn & 63;
      dF[(((size_t)b_ * NH + h_) * SS + s_) * HD + d_] = v;
    }
  }
}

// ---------------------------------------------------------------------------
// Fused attention: one (b,h) x 16 queries, 512 thr / 8 waves, XCD-swizzled.
// r9: score loop unroll 4; PV = 16-deep batched gather prefetch.
// Selection (one-shot 512-bin bucket + exact boundary ranking) unchanged.
// ---------------------------------------------------------------------------
__global__ __launch_bounds__(512, 4) void attn_topk(
    const bf16_t* __restrict__ qhg, const bf16_t* __restrict__ qmg,
    const bf16_t* __restrict__ qlg,
    const bf16_t* __restrict__ khg, const bf16_t* __restrict__ kmg,
    const bf16_t* __restrict__ klg,
    const float*  __restrict__ vg,
    bf16_t* __restrict__ attnH, bf16_t* __restrict__ attnM)
{
  __shared__ float sc[16 * 1028];       // scores; later overlaid as scratch

  const int tid  = threadIdx.x;
  const int wv   = tid >> 6, lane = tid & 63;
  const int quad = lane >> 4, l16 = lane & 15;
  const int xcd = blockIdx.x & 7;
  const int g   = blockIdx.x >> 3;        // 0..255
  const int bh  = xcd + 8 * (g >> 6);     // 0..31 (bh pinned to XCD)
  const int qt  = g & 63;
  const int b_ = bh >> 4, h_ = bh & 15;
  const int q0 = qt * 16;

  // A-frags direct from global: lane holds q[m=l16][k=quad*8+j]
  const size_t qbase = ((size_t)bh * SS + q0 + l16) * HD + quad * 8;
  bf16x8 aH[2], aM[2], aL[2];
#pragma unroll
  for (int ks = 0; ks < 2; ks++) {
    aH[ks] = *(const bf16x8*)(qhg + qbase + ks * 32);
    aM[ks] = *(const bf16x8*)(qmg + qbase + ks * 32);
    aL[ks] = *(const bf16x8*)(qlg + qbase + ks * 32);
  }

  // ---- score phase: wave wv covers keys [wv*128, wv*128+128) ----
  const size_t kwb = ((size_t)bh * SS + wv * 128 + l16) * HD + quad * 8;
#pragma unroll 4
  for (int t2 = 0; t2 < 8; t2++) {
    const size_t kb = kwb + (size_t)t2 * 16 * HD;
    bf16x8 bH0 = *(const bf16x8*)(khg + kb);
    bf16x8 bH1 = *(const bf16x8*)(khg + kb + 32);
    bf16x8 bM0 = *(const bf16x8*)(kmg + kb);
    bf16x8 bM1 = *(const bf16x8*)(kmg + kb + 32);
    bf16x8 bL0 = *(const bf16x8*)(klg + kb);
    bf16x8 bL1 = *(const bf16x8*)(klg + kb + 32);
    f32x4 accA = {}, accB = {}, accC = {};
    accA = mfma16(aH[0], bH0, accA);             // hh, k-half 0
    accB = mfma16(aH[1], bH1, accB);             // hh, k-half 1
    accC = mfma16(aH[0], bM0, accC);             // hm
    accC = mfma16(aH[1], bM1, accC);
    accC = mfma16(aM[0], bH0, accC);             // mh
    accC = mfma16(aM[1], bH1, accC);
    accC = mfma16(aH[0], bL0, accC);             // hl
    accC = mfma16(aH[1], bL1, accC);
    accC = mfma16(aL[0], bH0, accC);             // lh
    accC = mfma16(aL[1], bH1, accC);
    accC = mfma16(aM[0], bM0, accC);             // mm
    accC = mfma16(aM[1], bM1, accC);
    int key = wv * 128 + t2 * 16 + l16;
#pragma unroll
    for (int r = 0; r < 4; r++)
      sc[(quad * 4 + r) * 1028 + key] = ((accA[r] + accB[r]) + accC[r]) * 0.125f;
  }
  __syncthreads();                        // all scores visible

  // preload both owned queries into registers, then sc becomes scratch
  float fv[2][16];
#pragma unroll
  for (int i = 0; i < 16; i++) {
    fv[0][i] = sc[wv * 1028 + i * 64 + lane];
    fv[1][i] = sc[(wv + 8) * 1028 + i * 64 + lane];
  }
  __syncthreads();                        // sc region free for scratch

  // scratch overlay on sc (16448 floats):
  uint32_t* bins  = (uint32_t*)sc + wv * 512;     // [0, 4096) floats
  float*    selWp = sc + 4096;                    // 16*64 fp32  [4096,5120)
  ushort*   selIp = (ushort*)(sc + 5120);         // 16*64 u16
  float*    candV = (float*)bins;                 // reuse bins after scan
  ushort*   candI = (ushort*)(bins + 64);

  const uint64_t lt = (1ull << lane) - 1ull;
  for (int qi = 0; qi < 2; qi++) {
    int q = qi * 8 + wv;
    const float* fq = fv[qi];
    // zero bins (512 u32 per wave)
    *(uint4*)(bins + lane * 8)     = uint4{0, 0, 0, 0};
    *(uint4*)(bins + lane * 8 + 4) = uint4{0, 0, 0, 0};
    wave_fence();
    // histogram: bin = clamp((int)(f*32+256), 0, 511) — monotone in f
#pragma unroll
    for (int i = 0; i < 16; i++) {
      int b = (int)fmaxf(0.f, fminf(511.f, fmaf(fq[i], 32.f, 256.f)));
      atomicAdd(bins + b, 1u);
    }
    wave_fence();
    // descending scan: lane covers bins [504-8*lane, 511-8*lane]
    int base = 504 - 8 * lane;
    uint4 h0 = *(const uint4*)(bins + base);
    uint4 h1 = *(const uint4*)(bins + base + 4);
    uint32_t s_l = h0.x + h0.y + h0.z + h0.w + h1.x + h1.y + h1.z + h1.w;
    uint32_t x = s_l;
#pragma unroll
    for (int off = 1; off < 64; off <<= 1) {
      uint32_t y = __shfl_up(x, off);
      if (lane >= off) x += y;
    }
    uint32_t P = x - s_l;               // count in bins strictly above lane's range
    uint32_t harr[8] = { h1.w, h1.z, h1.y, h1.x, h0.w, h0.z, h0.y, h0.x };
    uint32_t cb = P, G = 0;
    int foundc = -1;
#pragma unroll
    for (int c = 0; c < 8; c++) {
      uint32_t hc = harr[c];
      if (foundc < 0 && (int)cb < 64 && (int)(cb + hc) >= 64) { foundc = c; G = cb; }
      cb += hc;
    }
    uint64_t fm = __ballot(foundc >= 0);
    int src   = __ffsll((unsigned long long)fm) - 1;
    int Bstar = __shfl((foundc >= 0) ? (511 - 8 * lane - foundc) : 0, src);
    int Gs    = __shfl((int)G, src);
    int needed = 64 - Gs;
    wave_fence();                        // scan reads done before candV writes

    // pass 1: bin > Bstar -> selected (Gs total), slots [0, Gs)
    int pos = 0, cT = 0;
#pragma unroll
    for (int i = 0; i < 16; i++) {
      int b = (int)fmaxf(0.f, fminf(511.f, fmaf(fq[i], 32.f, 256.f)));
      bool hi = b > Bstar;
      bool cd = (b == Bstar);
      uint64_t hm = __ballot(hi);
      uint64_t em = __ballot(cd);
      int p  = pos + (int)__popcll(hm & lt);
      int cp = cT  + (int)__popcll(em & lt);
      if (hi) { selWp[q * 64 + p] = fq[i]; selIp[q * 64 + p] = (ushort)(i * 64 + lane); }
      if (cd && cp < 64) { candV[cp] = fq[i]; candI[cp] = (ushort)(i * 64 + lane); }
      pos += (int)__popcll(hm);
      cT  += (int)__popcll(em);
    }
    wave_fence();
    // exact ranking inside boundary bin (value desc, index asc)
    int C = cT < 64 ? cT : 64;
    float mv = candV[lane];
    int   mi = candI[lane];
    int rank = 0;
    for (int i = 0; i < C; i++) {        // LDS broadcast reads
      float ov = candV[i]; int oi = candI[i];
      rank += (ov > mv || (ov == mv && oi < mi)) ? 1 : 0;
    }
    bool take = (lane < C) && (rank < needed);
    uint64_t tm = __ballot(take);
    int slot = Gs + (int)__popcll(tm & lt);
    if (take) { selWp[q * 64 + slot] = mv; selIp[q * 64 + slot] = (ushort)mi; }
    wave_fence();
    // softmax over the 64 selected scores
    float sv = selWp[q * 64 + lane];
    float mx = sv;
#pragma unroll
    for (int off = 32; off >= 1; off >>= 1) mx = fmaxf(mx, __shfl_xor(mx, off));
    float e = __expf(sv - mx);
    float sum = e;
#pragma unroll
    for (int off = 32; off >= 1; off >>= 1) sum += __shfl_xor(sum, off);
    selWp[q * 64 + lane] = e / sum;
    wave_fence();
  }
  __syncthreads();   // PV reads other waves' selW/selIdx

  // ---- PV: thread t -> q = t>>5, j-half = (t>>4)&1, d-block = (t&15)*4 ----
  // 16-deep batched prefetch: LDS (w,idx) to regs, then 16 gathers in flight.
  {
    int q = tid >> 5, jh = (tid >> 4) & 1, dblk = (tid & 15) * 4;
    const float* vb = vg + (size_t)bh * SS * HD;
    f32x4 a4 = {};
#pragma unroll
    for (int bch = 0; bch < 2; bch++) {
      float wreg[16]; int ireg[16];
#pragma unroll
      for (int j = 0; j < 16; j++) {
        int jj = jh * 32 + bch * 16 + j;
        wreg[j] = selWp[q * 64 + jj];
        ireg[j] = selIp[q * 64 + jj];
      }
#pragma unroll
      for (int j = 0; j < 16; j++) {
        f32x4 v4 = *(const f32x4*)(vb + (size_t)ireg[j] * HD + dblk);
        a4 += wreg[j] * v4;
      }
    }
#pragma unroll
    for (int c = 0; c < 4; c++) a4[c] += __shfl_xor(a4[c], 16);
    if (jh == 0) {
      size_t dofs = ((size_t)b_ * SS + q0 + q) * EE + h_ * HD + dblk;
      bf16x4 oh, om;
#pragma unroll
      for (int j = 0; j < 4; j++) {
        bf16_t hh = (bf16_t)a4[j];
        oh[j] = hh;
        om[j] = (bf16_t)(a4[j] - (float)hh);
      }
      *(bf16x4*)(attnH + dofs) = oh;
      *(bf16x4*)(attnM + dofs) = om;
    }
  }
}

// ---------------------------------------------------------------------------
extern "C" void kernel_launch(void* const* d_in, const int* in_sizes, int n_in,
                              void* d_out, int out_size, void* d_ws, size_t ws_size,
                              hipStream_t stream)
{
  const float* x  = (const float*)d_in[0];
  const float* Wq = (const float*)d_in[1];
  const float* bq = (const float*)d_in[2];
  const float* Wk = (const float*)d_in[3];
  const float* bk = (const float*)d_in[4];
  const float* Wv = (const float*)d_in[5];
  const float* bv = (const float*)d_in[6];
  const float* Wo = (const float*)d_in[7];
  const float* bo = (const float*)d_in[8];

  bf16_t* base = (bf16_t*)d_ws;
  bf16_t *xh = base,            *xm = xh + NX_,  *xl = xm + NX_;
  bf16_t *wqh = base + 3*NX_,           *wqm = wqh + NW_, *wql = wqm + NW_;
  bf16_t *wkh = base + 3*NX_ + 3*NW_,   *wkm = wkh + NW_, *wkl = wkm + NW_;
  bf16_t *wvh = base + 3*NX_ + 6*NW_,   *wvm = wvh + NW_;
  bf16_t *woh = base + 3*NX_ + 9*NW_,   *wom = woh + NW_;
  bf16_t *p2 = base + 3*NX_ + 12*NW_;
  bf16_t *qh = p2,          *qm = qh + NX_, *ql = qm + NX_;
  bf16_t *kh = ql + NX_,    *km = kh + NX_, *kl = km + NX_;
  float  *vws = (float*)(kl + NX_);
  bf16_t *ath = (bf16_t*)(vws + NX_), *atm = ath + NX_;

  dim3 blk(256);
  presplit_all<<<dim3(6144), blk, 0, stream>>>(x, Wq, Wk, Wv, Wo, base);

  // fused Q+K: 128x64 tile, grid (16, 16, 2) = 512 blocks (2/CU)
  gemm_qk<<<dim3(EE / 64, (NB * SS) / 128, 2), blk, 0, stream>>>(
      xh, xm, xl, wqh, wqm, wql, wkh, wkm, wkl, bq, bk,
      qh, qm, ql, kh, km, kl);

  // V: 64x64 tile, grid (16, 32) = 512 blocks (2/CU)
  gemm_nl2<1><<<dim3(EE / 64, (NB * SS) / 64), blk, 0, stream>>>(
      xh, xm, wvh, wvm, bv, vws);

  attn_topk<<<dim3(NBH * (SS / 16)), dim3(512), 0, stream>>>(
      qh, qm, ql, kh, km, kl, vws, ath, atm);

  // O: 64x64 tile, grid (16, 32) = 512 blocks (2/CU)
  gemm_nl2<2><<<dim3(EE / 64, (NB * SS) / 64), blk, 0, stream>>>(
      ath, atm, woh, wom, bo, (float*)d_out);
}